// Round 4
// baseline (412.687 us; speedup 1.0000x reference)
//
#include <hip/hip_runtime.h>
#include <stdint.h>

typedef unsigned long long u64;
typedef unsigned int u32;
typedef unsigned short u16;
typedef u32 u32x4 __attribute__((ext_vector_type(4)));
typedef float f32x4 __attribute__((ext_vector_type(4)));
typedef int i32x4 __attribute__((ext_vector_type(4)));

// Fixed problem shape (N=100000, E=1600000, C_IN=C_OUT=128, NHEADS=4)
#define CIN 128
#define NN 100000
#define EE 1600000
#define NPART 8   // shadow partitions; blockIdx&7 ~ XCD round-robin alignment

__device__ __forceinline__ float bf2f(u16 v) {
    union { u32 u; float f; } cv;
    cv.u = ((u32)v) << 16;
    return cv.f;
}

__device__ __forceinline__ u16 f2bf(float f) {      // RNE f32 -> bf16
    u32 b = __float_as_uint(f);
    return (u16)((b + 0x7FFFu + ((b >> 16) & 1u)) >> 16);
}

// Order-preserving bf16 -> u16 map (sign-flip trick). (mono16<<48 | ~e)
// compares identically to the original mono32(s_j+s_i)<<32 | ~e key within a
// src group (s_j const per group; f32 add of two bf16s exact; ties identical).
__device__ __forceinline__ u16 mono16(u16 b) {
    return (b & 0x8000u) ? (u16)~b : (u16)(b | 0x8000u);
}

// ---------------------------------------------------------------------------
// k_s: zero x_out / seg / nm / shadow+approx; V table in LDS; mono16(s_i)
// table as ushort4 per node (bit-identical FMA order to the 204µs version).
__global__ __launch_bounds__(256, 4) void k_s(const u16* __restrict__ x,
                                              const u16* __restrict__ W,
                                              const u16* __restrict__ att,
                                              ushort4* __restrict__ sib,
                                              u32x4* __restrict__ xout16, int n_xout16,
                                              u32x4* __restrict__ seg16, int n_seg16,
                                              u32x4* __restrict__ sh16, int n_sh16,
                                              int* __restrict__ nm, int n_nodes) {
    int stride = gridDim.x * blockDim.x;
    int tid = blockIdx.x * blockDim.x + threadIdx.x;
    u32x4 z = { 0, 0, 0, 0 };
    for (int i = tid; i < n_xout16; i += stride) __builtin_nontemporal_store(z, &xout16[i]);
    for (int i = tid; i < n_seg16; i += stride) __builtin_nontemporal_store(z, &seg16[i]);
    for (int i = tid; i < n_sh16; i += stride) __builtin_nontemporal_store(z, &sh16[i]);
    for (int i = tid; i < n_nodes; i += stride) nm[i] = 0;

    // ---- V table in LDS (f32), w_i half only ----
    __shared__ float Vl[512];
    for (int slot = threadIdx.x; slot < 512; slot += 256) {
        int k = slot >> 2, head = slot & 3;
        float acc = 0.0f;
        #pragma unroll
        for (int c = 0; c < 32; ++c)
            acc += bf2f(W[k * CIN + head * 32 + c]) * bf2f(att[head * 64 + 32 + c]);
        Vl[slot] = acc;
    }
    __syncthreads();

    for (int n = tid; n < n_nodes; n += stride) {
        const uint4* row = (const uint4*)(x + (size_t)n * CIN);
        float acc[4];
        #pragma unroll
        for (int h = 0; h < 4; ++h) acc[h] = 0.0f;
        #pragma unroll 4
        for (int q = 0; q < 16; ++q) {
            uint4 v = row[q];
            u32 w[4] = { v.x, v.y, v.z, v.w };
            #pragma unroll
            for (int j = 0; j < 4; ++j) {
                float x0 = bf2f((u16)(w[j] & 0xFFFFu));
                float x1 = bf2f((u16)(w[j] >> 16));
                int k0 = q * 8 + j * 2;
                #pragma unroll
                for (int h = 0; h < 4; ++h) acc[h] += x0 * Vl[k0 * 4 + h];
                #pragma unroll
                for (int h = 0; h < 4; ++h) acc[h] += x1 * Vl[(k0 + 1) * 4 + h];
            }
        }
        ushort4 a;
        a.x = mono16(f2bf(acc[0])); a.y = mono16(f2bf(acc[1]));
        a.z = mono16(f2bf(acc[2])); a.w = mono16(f2bf(acc[3]));
        sib[n] = a;
    }
}

// ---------------------------------------------------------------------------
// Pass 1: racy per-partition shadow max. Plain read-test-store (NO atomics,
// L2 write-back cached). partition = blockIdx&7 ~ XCD under round-robin, so
// each partition's dirty shadow lines live on ~one XCD (no cross-XCD
// write-back clobber). Races only lose updates; every stored value is a
// genuine score -> shadow[slot] <= true max always (correctness-safe).
__global__ __launch_bounds__(256) void k_shadow(const int* __restrict__ ei,
                                                const ushort4* __restrict__ sib,
                                                ushort4* __restrict__ shp, int n_edges) {
    int e = blockIdx.x * blockDim.x + threadIdx.x;
    if (e >= n_edges) return;
    int src = __builtin_nontemporal_load(ei + e);
    int dst = __builtin_nontemporal_load(ei + n_edges + e);
    ushort4 m = sib[dst];
    ushort4* slot = shp + (size_t)(blockIdx.x & (NPART - 1)) * NN + src;
    ushort4 cur = *slot;
    if ((m.x > cur.x) | (m.y > cur.y) | (m.z > cur.z) | (m.w > cur.w)) {
        ushort4 nv;
        nv.x = m.x > cur.x ? m.x : cur.x;
        nv.y = m.y > cur.y ? m.y : cur.y;
        nv.z = m.z > cur.z ? m.z : cur.z;
        nv.w = m.w > cur.w ? m.w : cur.w;
        *slot = nv;
    }
}

// ---------------------------------------------------------------------------
// Pass 1.5: union the 8 partition shadows -> approx[src] (<= true max,
// usually exact). Kernel boundary provides the device-scope flush.
__global__ void k_reduce(const ushort4* __restrict__ shp,
                         ushort4* __restrict__ approx, int n_nodes) {
    int t = blockIdx.x * blockDim.x + threadIdx.x;
    if (t >= n_nodes) return;
    ushort4 a = shp[t];
    #pragma unroll
    for (int p = 1; p < NPART; ++p) {
        ushort4 b = shp[(size_t)p * NN + t];
        a.x = b.x > a.x ? b.x : a.x;
        a.y = b.y > a.y ? b.y : a.y;
        a.z = b.z > a.z ? b.z : a.z;
        a.w = b.w > a.w ? b.w : a.w;
    }
    approx[t] = a;
}

// ---------------------------------------------------------------------------
// Pass 2: filtered fire-and-forget atomics. Admit iff score >= approx
// (approx never exceeds true max -> all max-score edges admitted -> exact
// winner + exact tie-break via u64 atomicMax). ~1.0-1.5 admissions/slot
// instead of H(16)=3.4 -> ~3x fewer atomics than the 64.6µs round-0 kernel,
// and zero seg test-read traffic.
__global__ __launch_bounds__(256) void k_edge2(const int* __restrict__ ei,
                                               const ushort4* __restrict__ sib,
                                               const ushort4* __restrict__ approx,
                                               u64* __restrict__ seg, int n_edges) {
    int e = blockIdx.x * blockDim.x + threadIdx.x;
    if (e >= n_edges) return;
    int src = __builtin_nontemporal_load(ei + e);
    int dst = __builtin_nontemporal_load(ei + n_edges + e);
    ushort4 m = sib[dst];
    ushort4 ap = approx[src];
    u64 lo = (u64)(u32)~(u32)e;
    u64* r = seg + (size_t)src * 4;
    if (m.x >= ap.x) atomicMax(&r[0], ((u64)m.x << 48) | lo);
    if (m.y >= ap.y) atomicMax(&r[1], ((u64)m.y << 48) | lo);
    if (m.z >= ap.z) atomicMax(&r[2], ((u64)m.z << 48) | lo);
    if (m.w >= ap.w) atomicMax(&r[3], ((u64)m.w << 48) | lo);
}

// ---------------------------------------------------------------------------
// Fallback (ws too small): round-0-proven test-then-atomic single pass.
__global__ __launch_bounds__(256) void k_edge_fb(const int* __restrict__ ei,
                                                 const ushort4* __restrict__ sib,
                                                 u64* __restrict__ seg, int n_edges) {
    int e = blockIdx.x * blockDim.x + threadIdx.x;
    if (e >= n_edges) return;
    int src = __builtin_nontemporal_load(ei + e);
    int dst = __builtin_nontemporal_load(ei + n_edges + e);
    ushort4 m = sib[dst];
    u64 lo = (u64)(u32)~(u32)e;
    u64* r = seg + (size_t)src * 4;
    ulonglong2 c01 = *(const ulonglong2*)(r);
    ulonglong2 c23 = *(const ulonglong2*)(r + 2);
    u64 k0 = ((u64)m.x << 48) | lo;
    u64 k1 = ((u64)m.y << 48) | lo;
    u64 k2 = ((u64)m.z << 48) | lo;
    u64 k3 = ((u64)m.w << 48) | lo;
    if (k0 > c01.x) atomicMax(&r[0], k0);
    if (k1 > c01.y) atomicMax(&r[1], k1);
    if (k2 > c23.x) atomicMax(&r[2], k2);
    if (k3 > c23.y) atomicMax(&r[3], k3);
}

// ---------------------------------------------------------------------------
// Decode winning edge per (src,head); set node_mask[dst].
__global__ void k_select(const int* __restrict__ ei, const u64* __restrict__ seg,
                         int* __restrict__ nm, int n4, int n_edges) {
    int t = blockIdx.x * blockDim.x + threadIdx.x;
    if (t >= n4) return;
    u64 m = seg[t];
    if (m) {
        int e = (int)(~(u32)m);
        nm[ei[n_edges + e]] = 1;     // race-benign: all writers store 1
    }
}

// ---------------------------------------------------------------------------
// Fused epilogue: edge_keep (4 edges/thread, nontemporal f32x4) + node_mask
// f32 + batch_slices f32.
__global__ void k_final(const int* __restrict__ ei, const int* __restrict__ nm,
                        const int* __restrict__ slices, float* __restrict__ out,
                        int n_edges, int n_nodes, int ek_off, int nm_off, int sl_off) {
    int t = blockIdx.x * blockDim.x + threadIdx.x;
    int e0 = 4 * t;
    if (e0 < n_edges) {
        i32x4 srcs = __builtin_nontemporal_load(((const i32x4*)ei) + t);
        i32x4 dsts = __builtin_nontemporal_load(((const i32x4*)(ei + n_edges)) + t);
        f32x4 v;
        v.x = (nm[srcs.x] & nm[dsts.x]) ? 1.0f : 0.0f;
        v.y = (nm[srcs.y] & nm[dsts.y]) ? 1.0f : 0.0f;
        v.z = (nm[srcs.z] & nm[dsts.z]) ? 1.0f : 0.0f;
        v.w = (nm[srcs.w] & nm[dsts.w]) ? 1.0f : 0.0f;
        __builtin_nontemporal_store(v, &((f32x4*)(out + ek_off))[t]);
    }
    if (t < n_nodes) out[nm_off + t] = nm[t] ? 1.0f : 0.0f;
    if (t < 2) out[sl_off + t] = (float)slices[t];   // 0 and 100000, exact
}

// ---------------------------------------------------------------------------
extern "C" void kernel_launch(void* const* d_in, const int* in_sizes, int n_in,
                              void* d_out, int out_size, void* d_ws, size_t ws_size,
                              hipStream_t stream) {
    // Bind inputs by UNIQUE flat size (permutation-proof):
    const u16* x = nullptr; const int* ei = nullptr; const int* sl = nullptr;
    const u16* W = nullptr; const u16* att = nullptr;
    for (int i = 0; i < n_in; ++i) {
        switch (in_sizes[i]) {
            case NN * CIN:   x   = (const u16*)d_in[i]; break;
            case 2 * EE:     ei  = (const int*)d_in[i]; break;
            case 2:          sl  = (const int*)d_in[i]; break;
            case CIN * CIN:  W   = (const u16*)d_in[i]; break;
            case 256:        att = (const u16*)d_in[i]; break;
            default: break;
        }
    }
    if (!x || !ei || !sl || !W || !att) return;

    float* out = (float*)d_out;             // f32 concat, return order
    const int N = NN;
    const int E = EE;
    const int N4 = N * 4;

    // output layout (f32): [x_out N*128][edge_keep E][node_mask N][slices 2]
    const int ek_off = N * CIN;
    const int nm_off = ek_off + E;
    const int sl_off = nm_off + N;

    // workspace (16B-aligned offsets):
    //   sib    N*8      @ 0          (800,000)
    //   nm     N*4      @ 800,000    (400,000)
    //   seg    N4*8     @ 1,200,000  (3,200,000)
    //   shp    8*N*8    @ 4,400,000  (6,400,000)
    //   approx N*8      @ 10,800,000 (800,000)   total 11.6 MB
    char* ws = (char*)d_ws;
    ushort4* sib    = (ushort4*)(ws);
    int*     nm     = (int*)    (ws + 800000);
    u64*     seg    = (u64*)    (ws + 1200000);
    ushort4* shp    = (ushort4*)(ws + 4400000);
    ushort4* approx = (ushort4*)(ws + 10800000);
    const bool big = ws_size >= 11600000;

    const int n_xout16 = N * CIN / 4;        // u32x4 count, f32 x_out region
    const int n_seg16  = N4 / 2;             // u32x4 count, seg table
    const int n_sh16   = big ? (NPART * N * 8 + N * 8) / 16 : 0;  // shp+approx contiguous

    const int egrid = (E + 255) / 256;

    k_s<<<1280, 256, 0, stream>>>(x, W, att, sib,
                                  (u32x4*)out, n_xout16,
                                  (u32x4*)seg, n_seg16,
                                  (u32x4*)shp, n_sh16, nm, N);
    if (big) {
        k_shadow<<<egrid, 256, 0, stream>>>(ei, sib, shp, E);
        k_reduce<<<(N + 255) / 256, 256, 0, stream>>>(shp, approx, N);
        k_edge2<<<egrid, 256, 0, stream>>>(ei, sib, approx, seg, E);
    } else {
        k_edge_fb<<<egrid, 256, 0, stream>>>(ei, sib, seg, E);
    }
    k_select<<<(N4 + 255) / 256, 256, 0, stream>>>(ei, seg, nm, N4, E);
    k_final<<<(E / 4 + 255) / 256, 256, 0, stream>>>(ei, nm, sl, out, E, N, ek_off, nm_off, sl_off);
}

// Round 5
// 197.264 us; speedup vs baseline: 2.0921x; 2.0921x over previous
//
#include <hip/hip_runtime.h>
#include <stdint.h>

typedef unsigned long long u64;
typedef unsigned int u32;
typedef unsigned short u16;
typedef u32 u32x4 __attribute__((ext_vector_type(4)));
typedef float f32x4 __attribute__((ext_vector_type(4)));
typedef int i32x4 __attribute__((ext_vector_type(4)));

// Fixed problem shape (N=100000, E=1600000, C_IN=C_OUT=128, NHEADS=4)
#define CIN 128
#define NN 100000
#define EE 1600000

__device__ __forceinline__ float bf2f(u16 v) {
    union { u32 u; float f; } cv;
    cv.u = ((u32)v) << 16;
    return cv.f;
}

__device__ __forceinline__ u16 f2bf(float f) {      // RNE f32 -> bf16
    u32 b = __float_as_uint(f);
    return (u16)((b + 0x7FFFu + ((b >> 16) & 1u)) >> 16);
}

// Order-preserving bf16 -> u16 map (sign-flip trick). (mono16<<48 | ~e)
// compares identically to the original mono32(s_j+s_i)<<32 | ~e key within a
// src group (s_j const per group; f32 add of two bf16s exact; ties identical).
// Never 0 for finite scores -> key==0 means "empty slot".
__device__ __forceinline__ u16 mono16(u16 b) {
    return (b & 0x8000u) ? (u16)~b : (u16)(b | 0x8000u);
}

// ---------------------------------------------------------------------------
// k_s: zero seg / nm (x_out zeroing moved to k_edge, which is latency-bound
// with idle write BW); V table (W ⊗ att_i) in LDS; mono16(s_i) per node.
// FMA order per node bit-identical to all passing rounds.
__global__ __launch_bounds__(256, 4) void k_s(const u16* __restrict__ x,
                                              const u16* __restrict__ W,
                                              const u16* __restrict__ att,
                                              ushort4* __restrict__ sib,
                                              u32x4* __restrict__ seg16, int n_seg16,
                                              int* __restrict__ nm, int n_nodes) {
    int stride = gridDim.x * blockDim.x;
    int tid = blockIdx.x * blockDim.x + threadIdx.x;
    u32x4 z = { 0, 0, 0, 0 };
    for (int i = tid; i < n_seg16; i += stride) __builtin_nontemporal_store(z, &seg16[i]);
    for (int i = tid; i < n_nodes; i += stride) nm[i] = 0;

    // ---- V table in LDS (f32), w_i half only ----
    __shared__ float Vl[512];
    for (int slot = threadIdx.x; slot < 512; slot += 256) {
        int k = slot >> 2, head = slot & 3;
        float acc = 0.0f;
        #pragma unroll
        for (int c = 0; c < 32; ++c)
            acc += bf2f(W[k * CIN + head * 32 + c]) * bf2f(att[head * 64 + 32 + c]);
        Vl[slot] = acc;
    }
    __syncthreads();

    for (int n = tid; n < n_nodes; n += stride) {
        const uint4* row = (const uint4*)(x + (size_t)n * CIN);
        float acc[4];
        #pragma unroll
        for (int h = 0; h < 4; ++h) acc[h] = 0.0f;
        #pragma unroll 4
        for (int q = 0; q < 16; ++q) {
            uint4 v = row[q];
            u32 w[4] = { v.x, v.y, v.z, v.w };
            #pragma unroll
            for (int j = 0; j < 4; ++j) {
                float x0 = bf2f((u16)(w[j] & 0xFFFFu));
                float x1 = bf2f((u16)(w[j] >> 16));
                int k0 = q * 8 + j * 2;
                #pragma unroll
                for (int h = 0; h < 4; ++h) acc[h] += x0 * Vl[k0 * 4 + h];
                #pragma unroll
                for (int h = 0; h < 4; ++h) acc[h] += x1 * Vl[(k0 + 1) * 4 + h];
            }
        }
        ushort4 a;
        a.x = mono16(f2bf(acc[0])); a.y = mono16(f2bf(acc[1]));
        a.z = mono16(f2bf(acc[2])); a.w = mono16(f2bf(acc[3]));
        sib[n] = a;
    }
}

// ---------------------------------------------------------------------------
// Round-0-proven test-then-atomic single pass (measured law: dur ~ atomics /
// 25.6G/s + latency base; this structure had the lowest admission count,
// ~777K, of every variant measured r0-r4). 1 edge/thread; single 8B sib
// gather (s_i-only key). PLUS: grid-stride x_out zero prologue — 51.2 MB of
// NT stores hidden under the atomic/gather latency (kernel runs at 10-17%
// HBM BW otherwise; stores are independent of the edge dependency chain).
__global__ __launch_bounds__(256) void k_edge(const int* __restrict__ ei,
                                              const ushort4* __restrict__ sib,
                                              u64* __restrict__ seg,
                                              u32x4* __restrict__ xout16, int n_xout16,
                                              int n_edges) {
    int t = blockIdx.x * blockDim.x + threadIdx.x;
    int stride = gridDim.x * blockDim.x;
    u32x4 z = { 0, 0, 0, 0 };
    for (int i = t; i < n_xout16; i += stride) __builtin_nontemporal_store(z, &xout16[i]);

    int e = t;
    if (e >= n_edges) return;
    int src = ei[e], dst = ei[n_edges + e];
    ushort4 m = sib[dst];
    u64 lo = (u64)(u32)~(u32)e;
    u64* r = seg + (size_t)src * 4;
    ulonglong2 c01 = *(const ulonglong2*)(r);
    ulonglong2 c23 = *(const ulonglong2*)(r + 2);
    u64 k0 = ((u64)m.x << 48) | lo;
    u64 k1 = ((u64)m.y << 48) | lo;
    u64 k2 = ((u64)m.z << 48) | lo;
    u64 k3 = ((u64)m.w << 48) | lo;
    if (k0 > c01.x) atomicMax(&r[0], k0);
    if (k1 > c01.y) atomicMax(&r[1], k1);
    if (k2 > c23.x) atomicMax(&r[2], k2);
    if (k3 > c23.y) atomicMax(&r[3], k3);
}

// ---------------------------------------------------------------------------
// Decode winning edge per (src,head); set node_mask[dst].
__global__ void k_select(const int* __restrict__ ei, const u64* __restrict__ seg,
                         int* __restrict__ nm, int n4, int n_edges) {
    int t = blockIdx.x * blockDim.x + threadIdx.x;
    if (t >= n4) return;
    u64 m = seg[t];
    if (m) {
        int e = (int)(~(u32)m);
        nm[ei[n_edges + e]] = 1;     // race-benign: all writers store 1
    }
}

// ---------------------------------------------------------------------------
// Fused epilogue: edge_keep (4 edges/thread, nontemporal f32x4) + node_mask
// f32 + batch_slices f32.
__global__ void k_final(const int* __restrict__ ei, const int* __restrict__ nm,
                        const int* __restrict__ slices, float* __restrict__ out,
                        int n_edges, int n_nodes, int ek_off, int nm_off, int sl_off) {
    int t = blockIdx.x * blockDim.x + threadIdx.x;
    int e0 = 4 * t;
    if (e0 < n_edges) {
        i32x4 srcs = __builtin_nontemporal_load(((const i32x4*)ei) + t);
        i32x4 dsts = __builtin_nontemporal_load(((const i32x4*)(ei + n_edges)) + t);
        f32x4 v;
        v.x = (nm[srcs.x] & nm[dsts.x]) ? 1.0f : 0.0f;
        v.y = (nm[srcs.y] & nm[dsts.y]) ? 1.0f : 0.0f;
        v.z = (nm[srcs.z] & nm[dsts.z]) ? 1.0f : 0.0f;
        v.w = (nm[srcs.w] & nm[dsts.w]) ? 1.0f : 0.0f;
        __builtin_nontemporal_store(v, &((f32x4*)(out + ek_off))[t]);
    }
    if (t < n_nodes) out[nm_off + t] = nm[t] ? 1.0f : 0.0f;
    if (t < 2) out[sl_off + t] = (float)slices[t];   // 0 and 100000, exact
}

// ---------------------------------------------------------------------------
extern "C" void kernel_launch(void* const* d_in, const int* in_sizes, int n_in,
                              void* d_out, int out_size, void* d_ws, size_t ws_size,
                              hipStream_t stream) {
    // Bind inputs by UNIQUE flat size (permutation-proof):
    const u16* x = nullptr; const int* ei = nullptr; const int* sl = nullptr;
    const u16* W = nullptr; const u16* att = nullptr;
    for (int i = 0; i < n_in; ++i) {
        switch (in_sizes[i]) {
            case NN * CIN:   x   = (const u16*)d_in[i]; break;
            case 2 * EE:     ei  = (const int*)d_in[i]; break;
            case 2:          sl  = (const int*)d_in[i]; break;
            case CIN * CIN:  W   = (const u16*)d_in[i]; break;
            case 256:        att = (const u16*)d_in[i]; break;
            default: break;
        }
    }
    if (!x || !ei || !sl || !W || !att) return;

    float* out = (float*)d_out;             // f32 concat, return order
    const int N = NN;
    const int E = EE;
    const int N4 = N * 4;

    // output layout (f32): [x_out N*128][edge_keep E][node_mask N][slices 2]
    const int ek_off = N * CIN;
    const int nm_off = ek_off + E;
    const int sl_off = nm_off + N;

    // workspace (16B-aligned): sib N*8 | nm N*4 | seg N4*8  (4.4 MB)
    char* ws = (char*)d_ws;
    ushort4* sib = (ushort4*)(ws);
    int*     nm  = (int*)    (ws + (size_t)N * 8);
    u64*     seg = (u64*)    (ws + (size_t)N * 12);

    const int n_xout16 = N * CIN / 4;        // u32x4 count, f32 x_out region
    const int n_seg16  = N4 / 2;             // u32x4 count, seg table

    k_s<<<1280, 256, 0, stream>>>(x, W, att, sib,
                                  (u32x4*)seg, n_seg16, nm, N);
    k_edge<<<(E + 255) / 256, 256, 0, stream>>>(ei, sib, seg,
                                                (u32x4*)out, n_xout16, E);
    k_select<<<(N4 + 255) / 256, 256, 0, stream>>>(ei, seg, nm, N4, E);
    k_final<<<(E / 4 + 255) / 256, 256, 0, stream>>>(ei, nm, sl, out, E, N, ek_off, nm_off, sl_off);
}